// Round 4
// baseline (374.140 us; speedup 1.0000x reference)
//
#include <hip/hip_runtime.h>

typedef unsigned short u16;
typedef unsigned int u32;
typedef __attribute__((ext_vector_type(8))) short short8;
typedef __attribute__((ext_vector_type(4))) float f32x4;

constexpr int B = 2, L = 16, C = 64, S = 64, W = 128, R = 32, MH = 32;
constexpr int BL = B * L;        // 32
constexpr int SW = S * W;        // 8192
constexpr int CR = C * R;        // 2048
constexpr int F2 = C * R * 2;    // 4096

__device__ __forceinline__ float us2f(u16 h) { return __uint_as_float(((u32)h) << 16); }
__device__ __forceinline__ float bf_lo(u32 u) { return __uint_as_float(u << 16); }
__device__ __forceinline__ float bf_hi(u32 u) { return __uint_as_float(u & 0xffff0000u); }
__device__ __forceinline__ u16 f2bu(float f) {
  u32 u = __float_as_uint(f);
  u32 r = (u + 0x7fffu + ((u >> 16) & 1u)) >> 16;
  return (u16)r;
}
__device__ __forceinline__ u32 pack2(float lo, float hi) {
  return (u32)f2bu(lo) | ((u32)f2bu(hi) << 16);
}

// ---------------- prep: lam, gamma ----------------
__global__ void k_prep(const float* __restrict__ nu_log, const float* __restrict__ th_log,
                       const float* __restrict__ dnu, const float* __restrict__ dth,
                       float* __restrict__ lamr, float* __restrict__ lami,
                       float* __restrict__ gam) {
  int i = blockIdx.x * 256 + threadIdx.x;
  if (i >= CR) return;
  float nu = expf(nu_log[i] + dnu[i]);
  float th = expf(th_log[i] + dth[i]);
  float mag = expf(-nu);
  lamr[i] = mag * cosf(th);
  lami[i] = mag * sinf(th);
  gam[i] = sqrtf(fmaxf(1.0f - mag * mag, 1e-6f));
}

// ---------------- prep: effective conv kernel (fuse folded), MFMA-A-swizzled bf16 ----------------
__global__ void k_keff(const float* __restrict__ fuse_k, const float* __restrict__ fuse_b,
                       const float* __restrict__ convr_k, const float* __restrict__ convr_b,
                       const float* __restrict__ convi_k, const float* __restrict__ convi_b,
                       u16* __restrict__ keff_bf, float* __restrict__ biaseff) {
  int i = blockIdx.x * 256 + threadIdx.x;
  if (i < C * 2 * C * 9) {
    int o = i / (2 * C * 9);
    int rem = i - o * (2 * C * 9);
    int cin2 = rem / 9;
    int seg = rem - cin2 * 9;
    const float* ck = (cin2 < C) ? convr_k : convi_k;
    int cin = cin2 & (C - 1);
    int fbase = o * 2 * C + ((cin2 < C) ? 0 : C);
    float acc = 0.f;
    for (int m = 0; m < C; ++m)
      acc += fuse_k[fbase + m] * ck[(m * C + cin) * 9 + seg];
    int kstep = cin2 >> 5;
    int kk = cin2 & 31;
    int lane = (o & 15) | ((kk >> 3) << 4);
    int j = kk & 7;
    int m_tile = o >> 4;
    keff_bf[((((seg * 4 + kstep) * 4 + m_tile) * 64 + lane) << 3) + j] = f2bu(acc);
  } else if (i < C * 2 * C * 9 + C) {
    int o = i - C * 2 * C * 9;
    float acc = fuse_b[o];
    for (int m = 0; m < C; ++m) {
      acc += fuse_k[o * 2 * C + m] * convr_b[m];
      acc += fuse_k[o * 2 * C + C + m] * convi_b[m];
    }
    biaseff[o] = acc;
  }
}

// ---------------- prep: projection matrix real-stacked bf16 [m=128][k=128] ----------------
__global__ void k_apack(const float* __restrict__ pWr, const float* __restrict__ pWi,
                        u16* __restrict__ aproj) {
  int i = blockIdx.x * 256 + threadIdx.x;
  if (i >= 128 * 128) return;
  int m = i >> 7, k = i & 127;
  int c = k >> 1, im = k & 1;
  int o = m & 63;
  float v;
  if (m < 64) v = im ? -pWi[o * 64 + c] : pWr[o * 64 + c];
  else        v = im ?  pWr[o * 64 + c] : pWi[o * 64 + c];
  aproj[i] = f2bu(v);
}

// ---------------- MLP -> forcing ----------------
// grid = BL * 16: w2 tile (32x256) staged in LDS; hidden layer recomputed per
// block. (Old 32-block version was latency-serialized at 1.4% occupancy, 96us.)
__global__ __launch_bounds__(256) void k_mlp(
    const float* __restrict__ ctx, const float* __restrict__ w1, const float* __restrict__ b1,
    const float* __restrict__ w2, const float* __restrict__ b2, const float* __restrict__ fscale,
    float* __restrict__ forcing) {
  int bl = blockIdx.x >> 4;
  int kt = blockIdx.x & 15;
  int k0 = kt * 256;
  __shared__ float cv[C];
  __shared__ float hid[MH];
  __shared__ float lw2[MH * 256];
  int t = threadIdx.x;
  if (t < C) cv[t] = ctx[bl * C + t];
  for (int i = t; i < MH * 64; i += 256) {
    int j = i >> 6, q = i & 63;
    ((float4*)lw2)[i] = ((const float4*)(w2 + (size_t)j * F2 + k0))[q];
  }
  __syncthreads();
  if (t < MH) {
    float a = b1[t];
    for (int c2 = 0; c2 < C; ++c2) a += cv[c2] * w1[c2 * MH + t];
    hid[t] = tanhf(a);
  }
  __syncthreads();
  float scale = fscale[0];
  float a = b2[k0 + t];
#pragma unroll
  for (int j = 0; j < MH; ++j) a += hid[j] * lw2[j * 256 + t];
  forcing[(size_t)bl * F2 + k0 + t] = scale * a;
}

// ---------------- MFMA encode (+ ctx fused): per (b,l,c) block ----------------
__global__ __launch_bounds__(256) void k_enc(
    const float* __restrict__ x,
    const float* __restrict__ Vr, const float* __restrict__ Vi,
    const float* __restrict__ Ur, const float* __restrict__ Ui,
    float* __restrict__ ctx, float* __restrict__ u) {
  int blc = blockIdx.x;
  int c = blc & (C - 1);
  __shared__ __align__(16) char smem[17408 * 2 + 16384 + 64];
  u16* xt = (u16*)smem;                    // [64][136] A = x[s][w] bf16
  u16* bt = (u16*)(smem + 17408);          // [64][136] B rows
  float* uldr = (float*)(smem + 34816);    // [2048] U real [s*32+r]
  float* uldi = uldr + 2048;               // [2048] U imag
  float* y1  = (float*)smem;               // alias xt: [64][65] f32
  float* part = (float*)(smem + 17408);    // alias bt: [8][64]
  float* red = (float*)(smem + 17408 * 2 + 16384);  // [16]
  int t = threadIdx.x;
  int lane = t & 63, wv = t >> 6;
  float sm = 0.f;
  {
    const float4* xp = (const float4*)(x + (size_t)blc * SW);
    for (int i = t; i < SW / 4; i += 256) {
      float4 v = xp[i];
      sm += v.x + v.y + v.z + v.w;
      int idx = i * 4, s = idx >> 7, w = idx & 127;
      u32* d = (u32*)&xt[s * 136 + w];
      d[0] = pack2(v.x, v.y);
      d[1] = pack2(v.z, v.w);
    }
  }
#pragma unroll
  for (int o = 32; o > 0; o >>= 1) sm += __shfl_down(sm, o, 64);
  if (lane == 0) red[wv] = sm;
  {
    const float* vrp = Vr + (size_t)c * 4096;
    const float* vip = Vi + (size_t)c * 4096;
    for (int i = t; i < 4096; i += 256) {
      int w = i >> 5, r = i & 31;
      bt[r * 136 + w]        = f2bu(vrp[i]);
      bt[(32 + r) * 136 + w] = f2bu(-vip[i]);
    }
  }
  {
    const float* urp = Ur + (size_t)c * 2048;
    const float* uip = Ui + (size_t)c * 2048;
    for (int i = t; i < 2048; i += 256) { uldr[i] = urp[i]; uldi[i] = uip[i]; }
  }
  __syncthreads();
  if (t == 0) ctx[blc] = (red[0] + red[1] + red[2] + red[3]) * (1.f / SW);
  int quad = lane >> 4, l15 = lane & 15;
  f32x4 zf = {0.f, 0.f, 0.f, 0.f};
  f32x4 acc[4] = {zf, zf, zf, zf};
#pragma unroll
  for (int ks = 0; ks < 4; ++ks) {
    int kofs = ks * 32 + quad * 8;
    short8 bf = *(const short8*)&bt[(wv * 16 + l15) * 136 + kofs];
#pragma unroll
    for (int mt = 0; mt < 4; ++mt) {
      short8 af = *(const short8*)&xt[(mt * 16 + l15) * 136 + kofs];
      acc[mt] = __builtin_amdgcn_mfma_f32_16x16x32_bf16(af, bf, acc[mt], 0, 0, 0);
    }
  }
  __syncthreads();
#pragma unroll
  for (int mt = 0; mt < 4; ++mt)
#pragma unroll
    for (int reg = 0; reg < 4; ++reg)
      y1[(mt * 16 + quad * 4 + reg) * 65 + wv * 16 + l15] = acc[mt][reg];
  __syncthreads();
  {
    int r = t & 31, sg = t >> 5;
    float pr = 0.f, pi = 0.f;
#pragma unroll
    for (int k = 0; k < 8; ++k) {
      int s = sg * 8 + k;
      float yr = y1[s * 65 + r], yi = y1[s * 65 + 32 + r];
      float ur = uldr[s * 32 + r], ui = uldi[s * 32 + r];
      pr += ur * yr + ui * yi;
      pi += ur * yi - ui * yr;
    }
    part[sg * 64 + r * 2]     = pr;
    part[sg * 64 + r * 2 + 1] = pi;
  }
  __syncthreads();
  if (t < 32) {
    float pr = 0.f, pi = 0.f;
#pragma unroll
    for (int sg = 0; sg < 8; ++sg) {
      pr += part[sg * 64 + t * 2];
      pi += part[sg * 64 + t * 2 + 1];
    }
    u[((size_t)blc * R + t) * 2]     = pr;
    u[((size_t)blc * R + t) * 2 + 1] = pi;
  }
}

// ---------------- diagonal scan over L (applies gamma*(1+forcing)) ----------------
__global__ void k_scan(const float* __restrict__ lamr, const float* __restrict__ lami,
                       const float* __restrict__ gam, const float* __restrict__ forcing,
                       const float* __restrict__ u, float* __restrict__ h) {
  int i = blockIdx.x * 256 + threadIdx.x;
  if (i >= B * CR) return;
  int b = i / CR;
  int cr = i - b * CR;
  float lr = lamr[cr], li = lami[cr], g = gam[cr];
  float hr = 0.f, hi = 0.f;
  for (int l = 0; l < L; ++l) {
    size_t off = ((size_t)(b * L + l) * CR + cr) * 2;
    float ur0 = u[off], ui0 = u[off + 1];
    float fr = forcing[off], fi = forcing[off + 1];
    float ofr = 1.f + fr;
    float ur = g * (ur0 * ofr - ui0 * fi);
    float ui = g * (ur0 * fi + ui0 * ofr);
    float nr = lr * hr - li * hi + ur;
    float ni = lr * hi + li * hr + ui;
    hr = nr; hi = ni;
    h[off] = hr; h[off + 1] = hi;
  }
}

// ---------------- MFMA decode: per (bl,c), Y[s,w] = (h*U)[s,:] x V[w,:]^T ----------------
__global__ __launch_bounds__(256) void k_decode(
    const float* __restrict__ h,
    const float* __restrict__ Ur, const float* __restrict__ Ui,
    const float* __restrict__ Vr, const float* __restrict__ Vi,
    u32* __restrict__ y_cm32, int bl_base) {
  int bid = blockIdx.x;
  int c = bid & 63;
  int blh = bid >> 6;
  int bl = bl_base + blh;
  __shared__ __align__(16) u16 ldA[64 * 72];
  __shared__ __align__(16) u16 ldBr[128 * 72];
  __shared__ __align__(16) u16 ldBi[128 * 72];
  int t = threadIdx.x;
  {
    const float* hp = h + ((size_t)(bl * C + c) * R) * 2;
    const float* urp = Ur + (size_t)c * (S * R);
    const float* uip = Ui + (size_t)c * (S * R);
    for (int p = t; p < S * R; p += 256) {
      int s = p >> 5, r = p & 31;
      float hr = hp[r * 2], hi = hp[r * 2 + 1];
      float ur = urp[p], ui = uip[p];
      ldA[s * 72 + r]      = f2bu(hr * ur - hi * ui);
      ldA[s * 72 + 32 + r] = f2bu(hr * ui + hi * ur);
    }
  }
  {
    const float* vrp = Vr + (size_t)c * (W * R);
    const float* vip = Vi + (size_t)c * (W * R);
    for (int p = t; p < W * R; p += 256) {
      int w = p >> 5, r = p & 31;
      float vr = vrp[p], vi = vip[p];
      ldBr[w * 72 + r]      = f2bu(vr);
      ldBr[w * 72 + 32 + r] = f2bu(-vi);
      ldBi[w * 72 + r]      = f2bu(vi);
      ldBi[w * 72 + 32 + r] = f2bu(vr);
    }
  }
  __syncthreads();
  int lane = t & 63, q = t >> 6;
  int quad = lane >> 4, l15 = lane & 15;
  f32x4 zf = {0.f, 0.f, 0.f, 0.f};
  f32x4 accr[4][2], acci[4][2];
#pragma unroll
  for (int mt = 0; mt < 4; ++mt)
#pragma unroll
    for (int nt = 0; nt < 2; ++nt) { accr[mt][nt] = zf; acci[mt][nt] = zf; }
#pragma unroll
  for (int ks = 0; ks < 2; ++ks) {
    int kofs = ks * 32 + quad * 8;
    short8 af[4];
#pragma unroll
    for (int mt = 0; mt < 4; ++mt)
      af[mt] = *(const short8*)&ldA[(mt * 16 + l15) * 72 + kofs];
#pragma unroll
    for (int nt = 0; nt < 2; ++nt) {
      int wrow = q * 32 + nt * 16 + l15;
      short8 br = *(const short8*)&ldBr[wrow * 72 + kofs];
      short8 bi = *(const short8*)&ldBi[wrow * 72 + kofs];
#pragma unroll
      for (int mt = 0; mt < 4; ++mt) {
        accr[mt][nt] = __builtin_amdgcn_mfma_f32_16x16x32_bf16(af[mt], br, accr[mt][nt], 0, 0, 0);
        acci[mt][nt] = __builtin_amdgcn_mfma_f32_16x16x32_bf16(af[mt], bi, acci[mt][nt], 0, 0, 0);
      }
    }
  }
  u32* dst = y_cm32 + ((size_t)(blh * 64 + c) << 13);
#pragma unroll
  for (int mt = 0; mt < 4; ++mt) {
#pragma unroll
    for (int nt = 0; nt < 2; ++nt) {
      int w = q * 32 + nt * 16 + l15;
#pragma unroll
      for (int reg = 0; reg < 4; ++reg) {
        int s = mt * 16 + quad * 4 + reg;
        dst[s * 128 + w] = pack2(accr[mt][nt][reg], acci[mt][nt][reg]);
      }
    }
  }
}

// ---------------- MFMA projection GEMM: M=128 ch_out, K=128, N=512/block -> NHWC ----------------
__global__ __launch_bounds__(256) void k_proj(
    const u32* __restrict__ y_cm32, const u16* __restrict__ aproj,
    const float* __restrict__ pbr, const float* __restrict__ pbi,
    u16* __restrict__ ynhwc, int bl_base) {
  int bid = blockIdx.x;
  int ntile = bid & 15;
  int blh = bid >> 4;
  int bl = bl_base + blh;
  __shared__ __align__(16) u16 lda[128 * 136];
  __shared__ __align__(16) u32 ldb[128 * 68];
  __shared__ float ldbias[128];
  int t = threadIdx.x;
  for (int i = t; i < 128 * 16; i += 256) {
    int m = i >> 4, qq = i & 15;
    ((uint4*)&lda[m * 136])[qq] = ((const uint4*)&aproj[m * 128])[qq];
  }
  if (t < 128) ldbias[t] = t < 64 ? pbr[t] : pbi[t - 64];

  int lane = t & 63, wv = t >> 6;
  int quad = lane >> 4, l15 = lane & 15;
  int cidx = t & 63, seg = t >> 6;
  f32x4 zf = {0.f, 0.f, 0.f, 0.f};

  for (int chunk = 0; chunk < 4; ++chunk) {
    int n0 = ntile * 512 + chunk * 128;
    __syncthreads();
    {
      const uint4* src = (const uint4*)(y_cm32 + (((size_t)(blh * 64 + cidx)) << 13) + n0 + seg * 32);
      u32 tmp[32];
#pragma unroll
      for (int qq = 0; qq < 8; ++qq) {
        uint4 v = src[qq];
        tmp[qq * 4] = v.x; tmp[qq * 4 + 1] = v.y; tmp[qq * 4 + 2] = v.z; tmp[qq * 4 + 3] = v.w;
      }
#pragma unroll
      for (int j = 0; j < 32; ++j)
        ldb[(seg * 32 + j) * 68 + cidx] = tmp[j];
    }
    __syncthreads();
    f32x4 acc[8][2];
#pragma unroll
    for (int mt = 0; mt < 8; ++mt) { acc[mt][0] = zf; acc[mt][1] = zf; }
    const u16* ldb16 = (const u16*)ldb;
#pragma unroll
    for (int ks = 0; ks < 4; ++ks) {
      int kofs = ks * 32 + quad * 8;
      short8 af[8];
#pragma unroll
      for (int mt = 0; mt < 8; ++mt)
        af[mt] = *(const short8*)&lda[(mt * 16 + l15) * 136 + kofs];
#pragma unroll
      for (int nt = 0; nt < 2; ++nt) {
        int nrow = wv * 32 + nt * 16 + l15;
        short8 bf = *(const short8*)&ldb16[nrow * 136 + kofs];
#pragma unroll
        for (int mt = 0; mt < 8; ++mt)
          acc[mt][nt] = __builtin_amdgcn_mfma_f32_16x16x32_bf16(af[mt], bf, acc[mt][nt], 0, 0, 0);
      }
    }
#pragma unroll
    for (int nt = 0; nt < 2; ++nt) {
      int n = n0 + wv * 32 + nt * 16 + l15;
      u16* drow = ynhwc + (((size_t)bl * SW + n) << 7);
#pragma unroll
      for (int mt = 0; mt < 8; ++mt) {
        int ch = mt * 16 + quad * 4;
        u32 lo = pack2(acc[mt][nt][0] + ldbias[ch],     acc[mt][nt][1] + ldbias[ch + 1]);
        u32 hi = pack2(acc[mt][nt][2] + ldbias[ch + 2], acc[mt][nt][3] + ldbias[ch + 3]);
        u32* dp = (u32*)(drow + ch);
        dp[0] = lo; dp[1] = hi;
      }
    }
  }
}

// ---------------- MFMA implicit-GEMM conv ----------------
// R4: K-split occupancy design. R3 lesson: halving A-L2 traffic at 2 blocks/CU
// REGRESSED (64.4->67.9us) -> kernel is latency-bound, waves/CU is the lever.
// Split the 128-ch reduction into two 64-ch passes so win LDS = [4][34][72]
// = 19.6 KB -> 8 blocks/CU (32 waves, 2x R2). __launch_bounds__(256,8) pins
// VGPR<=64. A-loads JIT (no dbuf): at 8 waves/SIMD TLP covers L2 latency.
// Same total ds_reads / A-loads / MFMAs / staged bytes as R2 (64.4us).
__global__ __launch_bounds__(256, 8) void k_conv(
    const u16* __restrict__ ynhwc, const u16* __restrict__ keff_bf,
    const float* __restrict__ biaseff, u16* __restrict__ fused) {
  int bid = blockIdx.x;
  int wt = bid & 3;
  int st = (bid >> 2) & 31;
  int bl = bid >> 7;
  int s0 = st * 2;
  int w0 = wt * 32;
  __shared__ __align__(16) u16 win[4][34][72];   // [s-row][w-col][64ch + 8 pad]
  int t = threadIdx.x;
  int c_lo = (w0 == 0) ? 1 : 0;
  int c_hi = (w0 == 96) ? 33 : 34;
  uint4 z4 = make_uint4(0u, 0u, 0u, 0u);

  int lane = t & 63;
  int wv = t >> 6;
  int mp = wv & 1;
  int np = wv >> 1;
  int quad = lane >> 4, l15 = lane & 15;
  int chq = quad * 8;

  f32x4 zf = {0.f, 0.f, 0.f, 0.f};
  f32x4 acc[2][2];  // [mi][nt], accumulates across both ch-passes
  acc[0][0] = zf; acc[0][1] = zf; acc[1][0] = zf; acc[1][1] = zf;
  const short8* ap = (const short8*)keff_bf;

#pragma unroll
  for (int p = 0; p < 2; ++p) {
    if (p) __syncthreads();   // pass-0 LDS reads complete before restage
    // stage ch-half p: 8 uint4 (64 ch) per (row, col)
    for (int rr = 0; rr < 4; ++rr) {
      int rs = s0 - 1 + rr;
      if (rs < 0 || rs >= S) {
        for (int i = t; i < 34 * 8; i += 256) {
          int col = i >> 3, q = i & 7;
          ((uint4*)&win[rr][col][0])[q] = z4;
        }
      } else {
        if (w0 == 0 && t < 8) ((uint4*)&win[rr][0][0])[t] = z4;
        if (w0 == 96 && t < 8) ((uint4*)&win[rr][33][0])[t] = z4;
        const uint4* src = (const uint4*)(ynhwc +
            (((size_t)bl * S + rs) * W + (w0 - 1 + c_lo)) * 128 + p * 64);
        int n4 = (c_hi - c_lo) * 8;
        for (int i = t; i < n4; i += 256) {
          int col = i >> 3, q = i & 7;
          ((uint4*)&win[rr][c_lo + col][0])[q] = src[col * 16 + q];
        }
      }
    }
    __syncthreads();

#pragma unroll
    for (int seg = 0; seg < 9; ++seg) {
      const int dr = seg / 3;
      const int dc = seg - dr * 3;
      const u16* b0base = &win[np + dr][l15 + dc][0];
      const u16* b1base = b0base + 16 * 72;
#pragma unroll
      for (int ks2 = 0; ks2 < 2; ++ks2) {
        const int ks = p * 2 + ks2;
        short8 a0 = ap[((seg * 4 + ks) * 4 + 2 * mp) * 64 + lane];
        short8 a1 = ap[((seg * 4 + ks) * 4 + 2 * mp + 1) * 64 + lane];
        short8 b0 = *(const short8*)(b0base + chq + ks2 * 32);
        short8 b1 = *(const short8*)(b1base + chq + ks2 * 32);
        acc[0][0] = __builtin_amdgcn_mfma_f32_16x16x32_bf16(a0, b0, acc[0][0], 0, 0, 0);
        acc[0][1] = __builtin_amdgcn_mfma_f32_16x16x32_bf16(a0, b1, acc[0][1], 0, 0, 0);
        acc[1][0] = __builtin_amdgcn_mfma_f32_16x16x32_bf16(a1, b0, acc[1][0], 0, 0, 0);
        acc[1][1] = __builtin_amdgcn_mfma_f32_16x16x32_bf16(a1, b1, acc[1][1], 0, 0, 0);
      }
    }
  }

  int s_out = s0 + np;
#pragma unroll
  for (int mi = 0; mi < 2; ++mi) {
#pragma unroll
    for (int reg = 0; reg < 4; ++reg) {
      int o = (2 * mp + mi) * 16 + quad * 4 + reg;
      float bias = biaseff[o];
      size_t rowoff = ((size_t)(bl * C + o) * S + s_out) * W;
      fused[rowoff + w0 + l15]      = f2bu(acc[mi][0][reg] + bias);
      fused[rowoff + w0 + 16 + l15] = f2bu(acc[mi][1][reg] + bias);
    }
  }
}

// ---------------- layernorm (stats in-kernel) + residual ----------------
__global__ __launch_bounds__(256) void k_ln(
    const u16* __restrict__ fused,
    const float* __restrict__ ln_g, const float* __restrict__ ln_b,
    const float* __restrict__ x, float* __restrict__ out) {
  int blc = blockIdx.x;
  __shared__ u16 fs[SW];
  __shared__ float red[12];
  int t = threadIdx.x;
  const uint4* fp = (const uint4*)(fused + (size_t)blc * SW);
  float sm = 0.f, sq = 0.f;
  for (int i = t; i < SW / 8; i += 256) {
    uint4 v = fp[i];
    ((uint4*)fs)[i] = v;
    float f0 = bf_lo(v.x), f1 = bf_hi(v.x), f2 = bf_lo(v.y), f3 = bf_hi(v.y);
    float f4 = bf_lo(v.z), f5 = bf_hi(v.z), f6 = bf_lo(v.w), f7 = bf_hi(v.w);
    sm += f0 + f1 + f2 + f3 + f4 + f5 + f6 + f7;
    sq += f0 * f0 + f1 * f1 + f2 * f2 + f3 * f3 + f4 * f4 + f5 * f5 + f6 * f6 + f7 * f7;
  }
#pragma unroll
  for (int off = 32; off > 0; off >>= 1) {
    sm += __shfl_down(sm, off, 64);
    sq += __shfl_down(sq, off, 64);
  }
  int lane = t & 63, wid = t >> 6;
  if (lane == 0) { red[wid * 2] = sm; red[wid * 2 + 1] = sq; }
  __syncthreads();
  if (t == 0) {
    float S1 = red[0] + red[2] + red[4] + red[6];
    float S2 = red[1] + red[3] + red[5] + red[7];
    float mu = S1 * (1.f / SW);
    float var = S2 * (1.f / SW) - mu * mu;
    red[8] = mu;
    red[9] = rsqrtf(var + 1e-5f);
  }
  __syncthreads();
  float mu = red[8], rstd = red[9];
  const float* xp = x + (size_t)blc * SW;
  float* op = out + (size_t)blc * SW;
  for (int i = t; i < SW; i += 256)
    op[i] = (us2f(fs[i]) - mu) * rstd * ln_g[i] + ln_b[i] + xp[i];
}

extern "C" void kernel_launch(void* const* d_in, const int* in_sizes, int n_in,
                              void* d_out, int out_size, void* d_ws, size_t ws_size,
                              hipStream_t stream) {
  (void)in_sizes; (void)n_in; (void)out_size; (void)ws_size;
  const float* x       = (const float*)d_in[0];
  const float* nu_log  = (const float*)d_in[1];
  const float* th_log  = (const float*)d_in[2];
  const float* dnu     = (const float*)d_in[3];
  const float* dth     = (const float*)d_in[4];
  const float* w1      = (const float*)d_in[5];
  const float* b1      = (const float*)d_in[6];
  const float* w2      = (const float*)d_in[7];
  const float* b2      = (const float*)d_in[8];
  const float* fscale  = (const float*)d_in[9];
  const float* Ur      = (const float*)d_in[10];
  const float* Ui      = (const float*)d_in[11];
  const float* Vr      = (const float*)d_in[12];
  const float* Vi      = (const float*)d_in[13];
  const float* pWr     = (const float*)d_in[14];
  const float* pWi     = (const float*)d_in[15];
  const float* pbr     = (const float*)d_in[16];
  const float* pbi     = (const float*)d_in[17];
  const float* convr_k = (const float*)d_in[18];
  const float* convr_b = (const float*)d_in[19];
  const float* convi_k = (const float*)d_in[20];
  const float* convi_b = (const float*)d_in[21];
  const float* fuse_k  = (const float*)d_in[22];
  const float* fuse_b  = (const float*)d_in[23];
  const float* ln_g    = (const float*)d_in[24];
  const float* ln_b    = (const float*)d_in[25];
  float* out = (float*)d_out;

  char* ws = (char*)d_ws;
  float* lamr    = (float*)ws;
  float* lami    = lamr + 2048;
  float* gam     = lami + 2048;
  float* biaseff = gam + 2048;        // 64
  float* ctx     = biaseff + 64;      // 2048
  float* forcing = ctx + 2048;        // 131072
  float* ubuf    = forcing + 131072;  // 131072
  float* hbuf    = ubuf + 131072;     // 131072
  u16* keff_bf   = (u16*)(hbuf + 131072);       // 73728 u16 (144 KB)
  u16* aproj     = keff_bf + 73728;             // 16384 u16 (32 KB)
  size_t off = ((size_t)((char*)(aproj + 16384) - ws) + 255) & ~(size_t)255;
  u32* y_cm32    = (u32*)(ws + off);            // 32 MB (half-batch)
  u16* fused     = (u16*)y_cm32;                // ALIAS: live only after y_cm32 dead
  u16* ynhwc     = (u16*)(ws + off + (size_t)32 * 1024 * 1024);  // 64 MB
  // total ws ~ 97.8 MB

  k_prep<<<8, 256, 0, stream>>>(nu_log, th_log, dnu, dth, lamr, lami, gam);
  k_keff<<<289, 256, 0, stream>>>(fuse_k, fuse_b, convr_k, convr_b, convi_k, convi_b,
                                  keff_bf, biaseff);
  k_apack<<<64, 256, 0, stream>>>(pWr, pWi, aproj);
  k_enc<<<BL * C, 256, 0, stream>>>(x, Vr, Vi, Ur, Ui, ctx, ubuf);
  k_mlp<<<BL * 16, 256, 0, stream>>>(ctx, w1, b1, w2, b2, fscale, forcing);
  k_scan<<<16, 256, 0, stream>>>(lamr, lami, gam, forcing, ubuf, hbuf);
  k_decode<<<1024, 256, 0, stream>>>(hbuf, Ur, Ui, Vr, Vi, y_cm32, 0);
  k_proj<<<256, 256, 0, stream>>>(y_cm32, aproj, pbr, pbi, ynhwc, 0);
  k_decode<<<1024, 256, 0, stream>>>(hbuf, Ur, Ui, Vr, Vi, y_cm32, 16);
  k_proj<<<256, 256, 0, stream>>>(y_cm32, aproj, pbr, pbi, ynhwc, 16);
  k_conv<<<4096, 256, 0, stream>>>(ynhwc, keff_bf, biaseff, fused);
  k_ln<<<BL * C, 256, 0, stream>>>(fused, ln_g, ln_b, x, out);
}

// Round 5
// 347.474 us; speedup vs baseline: 1.0767x; 1.0767x over previous
//
#include <hip/hip_runtime.h>

typedef unsigned short u16;
typedef unsigned int u32;
typedef __attribute__((ext_vector_type(8))) short short8;
typedef __attribute__((ext_vector_type(4))) float f32x4;

constexpr int B = 2, L = 16, C = 64, S = 64, W = 128, R = 32, MH = 32;
constexpr int BL = B * L;        // 32
constexpr int SW = S * W;        // 8192
constexpr int CR = C * R;        // 2048
constexpr int F2 = C * R * 2;    // 4096

__device__ __forceinline__ float us2f(u16 h) { return __uint_as_float(((u32)h) << 16); }
__device__ __forceinline__ float bf_lo(u32 u) { return __uint_as_float(u << 16); }
__device__ __forceinline__ float bf_hi(u32 u) { return __uint_as_float(u & 0xffff0000u); }
__device__ __forceinline__ u16 f2bu(float f) {
  u32 u = __float_as_uint(f);
  u32 r = (u + 0x7fffu + ((u >> 16) & 1u)) >> 16;
  return (u16)r;
}
__device__ __forceinline__ u32 pack2(float lo, float hi) {
  return (u32)f2bu(lo) | ((u32)f2bu(hi) << 16);
}

// ---------------- prep: lam, gamma ----------------
__global__ void k_prep(const float* __restrict__ nu_log, const float* __restrict__ th_log,
                       const float* __restrict__ dnu, const float* __restrict__ dth,
                       float* __restrict__ lamr, float* __restrict__ lami,
                       float* __restrict__ gam) {
  int i = blockIdx.x * 256 + threadIdx.x;
  if (i >= CR) return;
  float nu = expf(nu_log[i] + dnu[i]);
  float th = expf(th_log[i] + dth[i]);
  float mag = expf(-nu);
  lamr[i] = mag * cosf(th);
  lami[i] = mag * sinf(th);
  gam[i] = sqrtf(fmaxf(1.0f - mag * mag, 1e-6f));
}

// ---------------- prep: effective conv kernel (fuse folded), MFMA-A-swizzled bf16 ----------------
__global__ void k_keff(const float* __restrict__ fuse_k, const float* __restrict__ fuse_b,
                       const float* __restrict__ convr_k, const float* __restrict__ convr_b,
                       const float* __restrict__ convi_k, const float* __restrict__ convi_b,
                       u16* __restrict__ keff_bf, float* __restrict__ biaseff) {
  int i = blockIdx.x * 256 + threadIdx.x;
  if (i < C * 2 * C * 9) {
    int o = i / (2 * C * 9);
    int rem = i - o * (2 * C * 9);
    int cin2 = rem / 9;
    int seg = rem - cin2 * 9;
    const float* ck = (cin2 < C) ? convr_k : convi_k;
    int cin = cin2 & (C - 1);
    int fbase = o * 2 * C + ((cin2 < C) ? 0 : C);
    float acc = 0.f;
    for (int m = 0; m < C; ++m)
      acc += fuse_k[fbase + m] * ck[(m * C + cin) * 9 + seg];
    int kstep = cin2 >> 5;
    int kk = cin2 & 31;
    int lane = (o & 15) | ((kk >> 3) << 4);
    int j = kk & 7;
    int m_tile = o >> 4;
    keff_bf[((((seg * 4 + kstep) * 4 + m_tile) * 64 + lane) << 3) + j] = f2bu(acc);
  } else if (i < C * 2 * C * 9 + C) {
    int o = i - C * 2 * C * 9;
    float acc = fuse_b[o];
    for (int m = 0; m < C; ++m) {
      acc += fuse_k[o * 2 * C + m] * convr_b[m];
      acc += fuse_k[o * 2 * C + C + m] * convi_b[m];
    }
    biaseff[o] = acc;
  }
}

// ---------------- prep: projection matrix real-stacked bf16 [m=128][k=128] ----------------
__global__ void k_apack(const float* __restrict__ pWr, const float* __restrict__ pWi,
                        u16* __restrict__ aproj) {
  int i = blockIdx.x * 256 + threadIdx.x;
  if (i >= 128 * 128) return;
  int m = i >> 7, k = i & 127;
  int c = k >> 1, im = k & 1;
  int o = m & 63;
  float v;
  if (m < 64) v = im ? -pWi[o * 64 + c] : pWr[o * 64 + c];
  else        v = im ?  pWr[o * 64 + c] : pWi[o * 64 + c];
  aproj[i] = f2bu(v);
}

// ---------------- MLP -> forcing ----------------
// grid = BL * 16: w2 tile (32x256) staged in LDS; hidden layer recomputed per
// block. (Old 32-block version was latency-serialized at 1.4% occupancy, 96us.)
__global__ __launch_bounds__(256) void k_mlp(
    const float* __restrict__ ctx, const float* __restrict__ w1, const float* __restrict__ b1,
    const float* __restrict__ w2, const float* __restrict__ b2, const float* __restrict__ fscale,
    float* __restrict__ forcing) {
  int bl = blockIdx.x >> 4;
  int kt = blockIdx.x & 15;
  int k0 = kt * 256;
  __shared__ float cv[C];
  __shared__ float hid[MH];
  __shared__ float lw2[MH * 256];
  int t = threadIdx.x;
  if (t < C) cv[t] = ctx[bl * C + t];
  for (int i = t; i < MH * 64; i += 256) {
    int j = i >> 6, q = i & 63;
    ((float4*)lw2)[i] = ((const float4*)(w2 + (size_t)j * F2 + k0))[q];
  }
  __syncthreads();
  if (t < MH) {
    float a = b1[t];
    for (int c2 = 0; c2 < C; ++c2) a += cv[c2] * w1[c2 * MH + t];
    hid[t] = tanhf(a);
  }
  __syncthreads();
  float scale = fscale[0];
  float a = b2[k0 + t];
#pragma unroll
  for (int j = 0; j < MH; ++j) a += hid[j] * lw2[j * 256 + t];
  forcing[(size_t)bl * F2 + k0 + t] = scale * a;
}

// ---------------- MFMA encode (+ ctx fused): per (b,l,c) block ----------------
__global__ __launch_bounds__(256) void k_enc(
    const float* __restrict__ x,
    const float* __restrict__ Vr, const float* __restrict__ Vi,
    const float* __restrict__ Ur, const float* __restrict__ Ui,
    float* __restrict__ ctx, float* __restrict__ u) {
  int blc = blockIdx.x;
  int c = blc & (C - 1);
  __shared__ __align__(16) char smem[17408 * 2 + 16384 + 64];
  u16* xt = (u16*)smem;                    // [64][136] A = x[s][w] bf16
  u16* bt = (u16*)(smem + 17408);          // [64][136] B rows
  float* uldr = (float*)(smem + 34816);    // [2048] U real [s*32+r]
  float* uldi = uldr + 2048;               // [2048] U imag
  float* y1  = (float*)smem;               // alias xt: [64][65] f32
  float* part = (float*)(smem + 17408);    // alias bt: [8][64]
  float* red = (float*)(smem + 17408 * 2 + 16384);  // [16]
  int t = threadIdx.x;
  int lane = t & 63, wv = t >> 6;
  float sm = 0.f;
  {
    const float4* xp = (const float4*)(x + (size_t)blc * SW);
    for (int i = t; i < SW / 4; i += 256) {
      float4 v = xp[i];
      sm += v.x + v.y + v.z + v.w;
      int idx = i * 4, s = idx >> 7, w = idx & 127;
      u32* d = (u32*)&xt[s * 136 + w];
      d[0] = pack2(v.x, v.y);
      d[1] = pack2(v.z, v.w);
    }
  }
#pragma unroll
  for (int o = 32; o > 0; o >>= 1) sm += __shfl_down(sm, o, 64);
  if (lane == 0) red[wv] = sm;
  {
    const float* vrp = Vr + (size_t)c * 4096;
    const float* vip = Vi + (size_t)c * 4096;
    for (int i = t; i < 4096; i += 256) {
      int w = i >> 5, r = i & 31;
      bt[r * 136 + w]        = f2bu(vrp[i]);
      bt[(32 + r) * 136 + w] = f2bu(-vip[i]);
    }
  }
  {
    const float* urp = Ur + (size_t)c * 2048;
    const float* uip = Ui + (size_t)c * 2048;
    for (int i = t; i < 2048; i += 256) { uldr[i] = urp[i]; uldi[i] = uip[i]; }
  }
  __syncthreads();
  if (t == 0) ctx[blc] = (red[0] + red[1] + red[2] + red[3]) * (1.f / SW);
  int quad = lane >> 4, l15 = lane & 15;
  f32x4 zf = {0.f, 0.f, 0.f, 0.f};
  f32x4 acc[4] = {zf, zf, zf, zf};
#pragma unroll
  for (int ks = 0; ks < 4; ++ks) {
    int kofs = ks * 32 + quad * 8;
    short8 bf = *(const short8*)&bt[(wv * 16 + l15) * 136 + kofs];
#pragma unroll
    for (int mt = 0; mt < 4; ++mt) {
      short8 af = *(const short8*)&xt[(mt * 16 + l15) * 136 + kofs];
      acc[mt] = __builtin_amdgcn_mfma_f32_16x16x32_bf16(af, bf, acc[mt], 0, 0, 0);
    }
  }
  __syncthreads();
#pragma unroll
  for (int mt = 0; mt < 4; ++mt)
#pragma unroll
    for (int reg = 0; reg < 4; ++reg)
      y1[(mt * 16 + quad * 4 + reg) * 65 + wv * 16 + l15] = acc[mt][reg];
  __syncthreads();
  {
    int r = t & 31, sg = t >> 5;
    float pr = 0.f, pi = 0.f;
#pragma unroll
    for (int k = 0; k < 8; ++k) {
      int s = sg * 8 + k;
      float yr = y1[s * 65 + r], yi = y1[s * 65 + 32 + r];
      float ur = uldr[s * 32 + r], ui = uldi[s * 32 + r];
      pr += ur * yr + ui * yi;
      pi += ur * yi - ui * yr;
    }
    part[sg * 64 + r * 2]     = pr;
    part[sg * 64 + r * 2 + 1] = pi;
  }
  __syncthreads();
  if (t < 32) {
    float pr = 0.f, pi = 0.f;
#pragma unroll
    for (int sg = 0; sg < 8; ++sg) {
      pr += part[sg * 64 + t * 2];
      pi += part[sg * 64 + t * 2 + 1];
    }
    u[((size_t)blc * R + t) * 2]     = pr;
    u[((size_t)blc * R + t) * 2 + 1] = pi;
  }
}

// ---------------- diagonal scan over L (applies gamma*(1+forcing)) ----------------
__global__ void k_scan(const float* __restrict__ lamr, const float* __restrict__ lami,
                       const float* __restrict__ gam, const float* __restrict__ forcing,
                       const float* __restrict__ u, float* __restrict__ h) {
  int i = blockIdx.x * 256 + threadIdx.x;
  if (i >= B * CR) return;
  int b = i / CR;
  int cr = i - b * CR;
  float lr = lamr[cr], li = lami[cr], g = gam[cr];
  float hr = 0.f, hi = 0.f;
  for (int l = 0; l < L; ++l) {
    size_t off = ((size_t)(b * L + l) * CR + cr) * 2;
    float ur0 = u[off], ui0 = u[off + 1];
    float fr = forcing[off], fi = forcing[off + 1];
    float ofr = 1.f + fr;
    float ur = g * (ur0 * ofr - ui0 * fi);
    float ui = g * (ur0 * fi + ui0 * ofr);
    float nr = lr * hr - li * hi + ur;
    float ni = lr * hi + li * hr + ui;
    hr = nr; hi = ni;
    h[off] = hr; h[off + 1] = hi;
  }
}

// ---------------- MFMA decode: per (bl,c), Y[s,w] = (h*U)[s,:] x V[w,:]^T ----------------
__global__ __launch_bounds__(256) void k_decode(
    const float* __restrict__ h,
    const float* __restrict__ Ur, const float* __restrict__ Ui,
    const float* __restrict__ Vr, const float* __restrict__ Vi,
    u32* __restrict__ y_cm32, int bl_base) {
  int bid = blockIdx.x;
  int c = bid & 63;
  int blh = bid >> 6;
  int bl = bl_base + blh;
  __shared__ __align__(16) u16 ldA[64 * 72];
  __shared__ __align__(16) u16 ldBr[128 * 72];
  __shared__ __align__(16) u16 ldBi[128 * 72];
  int t = threadIdx.x;
  {
    const float* hp = h + ((size_t)(bl * C + c) * R) * 2;
    const float* urp = Ur + (size_t)c * (S * R);
    const float* uip = Ui + (size_t)c * (S * R);
    for (int p = t; p < S * R; p += 256) {
      int s = p >> 5, r = p & 31;
      float hr = hp[r * 2], hi = hp[r * 2 + 1];
      float ur = urp[p], ui = uip[p];
      ldA[s * 72 + r]      = f2bu(hr * ur - hi * ui);
      ldA[s * 72 + 32 + r] = f2bu(hr * ui + hi * ur);
    }
  }
  {
    const float* vrp = Vr + (size_t)c * (W * R);
    const float* vip = Vi + (size_t)c * (W * R);
    for (int p = t; p < W * R; p += 256) {
      int w = p >> 5, r = p & 31;
      float vr = vrp[p], vi = vip[p];
      ldBr[w * 72 + r]      = f2bu(vr);
      ldBr[w * 72 + 32 + r] = f2bu(-vi);
      ldBi[w * 72 + r]      = f2bu(vi);
      ldBi[w * 72 + 32 + r] = f2bu(vr);
    }
  }
  __syncthreads();
  int lane = t & 63, q = t >> 6;
  int quad = lane >> 4, l15 = lane & 15;
  f32x4 zf = {0.f, 0.f, 0.f, 0.f};
  f32x4 accr[4][2], acci[4][2];
#pragma unroll
  for (int mt = 0; mt < 4; ++mt)
#pragma unroll
    for (int nt = 0; nt < 2; ++nt) { accr[mt][nt] = zf; acci[mt][nt] = zf; }
#pragma unroll
  for (int ks = 0; ks < 2; ++ks) {
    int kofs = ks * 32 + quad * 8;
    short8 af[4];
#pragma unroll
    for (int mt = 0; mt < 4; ++mt)
      af[mt] = *(const short8*)&ldA[(mt * 16 + l15) * 72 + kofs];
#pragma unroll
    for (int nt = 0; nt < 2; ++nt) {
      int wrow = q * 32 + nt * 16 + l15;
      short8 br = *(const short8*)&ldBr[wrow * 72 + kofs];
      short8 bi = *(const short8*)&ldBi[wrow * 72 + kofs];
#pragma unroll
      for (int mt = 0; mt < 4; ++mt) {
        accr[mt][nt] = __builtin_amdgcn_mfma_f32_16x16x32_bf16(af[mt], br, accr[mt][nt], 0, 0, 0);
        acci[mt][nt] = __builtin_amdgcn_mfma_f32_16x16x32_bf16(af[mt], bi, acci[mt][nt], 0, 0, 0);
      }
    }
  }
  u32* dst = y_cm32 + ((size_t)(blh * 64 + c) << 13);
#pragma unroll
  for (int mt = 0; mt < 4; ++mt) {
#pragma unroll
    for (int nt = 0; nt < 2; ++nt) {
      int w = q * 32 + nt * 16 + l15;
#pragma unroll
      for (int reg = 0; reg < 4; ++reg) {
        int s = mt * 16 + quad * 4 + reg;
        dst[s * 128 + w] = pack2(accr[mt][nt][reg], acci[mt][nt][reg]);
      }
    }
  }
}

// ---------------- MFMA projection GEMM: M=128 ch_out, K=128, N=512/block -> NHWC ----------------
__global__ __launch_bounds__(256) void k_proj(
    const u32* __restrict__ y_cm32, const u16* __restrict__ aproj,
    const float* __restrict__ pbr, const float* __restrict__ pbi,
    u16* __restrict__ ynhwc, int bl_base) {
  int bid = blockIdx.x;
  int ntile = bid & 15;
  int blh = bid >> 4;
  int bl = bl_base + blh;
  __shared__ __align__(16) u16 lda[128 * 136];
  __shared__ __align__(16) u32 ldb[128 * 68];
  __shared__ float ldbias[128];
  int t = threadIdx.x;
  for (int i = t; i < 128 * 16; i += 256) {
    int m = i >> 4, qq = i & 15;
    ((uint4*)&lda[m * 136])[qq] = ((const uint4*)&aproj[m * 128])[qq];
  }
  if (t < 128) ldbias[t] = t < 64 ? pbr[t] : pbi[t - 64];

  int lane = t & 63, wv = t >> 6;
  int quad = lane >> 4, l15 = lane & 15;
  int cidx = t & 63, seg = t >> 6;
  f32x4 zf = {0.f, 0.f, 0.f, 0.f};

  for (int chunk = 0; chunk < 4; ++chunk) {
    int n0 = ntile * 512 + chunk * 128;
    __syncthreads();
    {
      const uint4* src = (const uint4*)(y_cm32 + (((size_t)(blh * 64 + cidx)) << 13) + n0 + seg * 32);
      u32 tmp[32];
#pragma unroll
      for (int qq = 0; qq < 8; ++qq) {
        uint4 v = src[qq];
        tmp[qq * 4] = v.x; tmp[qq * 4 + 1] = v.y; tmp[qq * 4 + 2] = v.z; tmp[qq * 4 + 3] = v.w;
      }
#pragma unroll
      for (int j = 0; j < 32; ++j)
        ldb[(seg * 32 + j) * 68 + cidx] = tmp[j];
    }
    __syncthreads();
    f32x4 acc[8][2];
#pragma unroll
    for (int mt = 0; mt < 8; ++mt) { acc[mt][0] = zf; acc[mt][1] = zf; }
    const u16* ldb16 = (const u16*)ldb;
#pragma unroll
    for (int ks = 0; ks < 4; ++ks) {
      int kofs = ks * 32 + quad * 8;
      short8 af[8];
#pragma unroll
      for (int mt = 0; mt < 8; ++mt)
        af[mt] = *(const short8*)&lda[(mt * 16 + l15) * 136 + kofs];
#pragma unroll
      for (int nt = 0; nt < 2; ++nt) {
        int nrow = wv * 32 + nt * 16 + l15;
        short8 bf = *(const short8*)&ldb16[nrow * 136 + kofs];
#pragma unroll
        for (int mt = 0; mt < 8; ++mt)
          acc[mt][nt] = __builtin_amdgcn_mfma_f32_16x16x32_bf16(af[mt], bf, acc[mt][nt], 0, 0, 0);
      }
    }
#pragma unroll
    for (int nt = 0; nt < 2; ++nt) {
      int n = n0 + wv * 32 + nt * 16 + l15;
      u16* drow = ynhwc + (((size_t)bl * SW + n) << 7);
#pragma unroll
      for (int mt = 0; mt < 8; ++mt) {
        int ch = mt * 16 + quad * 4;
        u32 lo = pack2(acc[mt][nt][0] + ldbias[ch],     acc[mt][nt][1] + ldbias[ch + 1]);
        u32 hi = pack2(acc[mt][nt][2] + ldbias[ch + 2], acc[mt][nt][3] + ldbias[ch + 3]);
        u32* dp = (u32*)(drow + ch);
        dp[0] = lo; dp[1] = hi;
      }
    }
  }
}

// ---------------- MFMA implicit-GEMM conv ----------------
// R5: w-tile=64 at R2's occupancy. Triangle of evidence: R2 (4 blk/CU, A-dbuf)
// = 64.4us; R3 (A halved, 2 blk/CU) = 67.9; R4 (8 blk/CU, VGPR=32, no dbuf)
// = 81.8. => per-wave ILP (dbuf) + >=4 blk/CU both required; now halve A
// traffic (1.18GB -> 0.59GB L2) by computing 64 w per block with the SAME
// A stream. ch-split staging keeps win = [4][66][72] = 38.0 KB -> 4 blk/CU.
// launch_bounds(256,4) caps VGPR at 128 (acc 32 + abuf 32 + addr ~ 100).
// Full 128B-line fused writes (w0..w0+63) avoid R4's write amplification.
__global__ __launch_bounds__(256, 4) void k_conv(
    const u16* __restrict__ ynhwc, const u16* __restrict__ keff_bf,
    const float* __restrict__ biaseff, u16* __restrict__ fused) {
  int bid = blockIdx.x;
  int wt = bid & 1;
  int st = (bid >> 1) & 31;
  int bl = bid >> 6;
  int s0 = st * 2;
  int w0 = wt * 64;
  __shared__ __align__(16) u16 win[4][66][72];   // [s-row][w-col][64ch + 8 pad]
  int t = threadIdx.x;
  // valid col range [c_lo, c_hi); wt=0: col0 = w=-1 (zero); wt=1: col65 = w=128 (zero)
  int c_lo = (wt == 0) ? 1 : 0;
  int c_hi = (wt == 0) ? 66 : 65;
  uint4 z4 = make_uint4(0u, 0u, 0u, 0u);

  int lane = t & 63;
  int wv = t >> 6;
  int mp = wv & 1;          // m-tile pair {2mp, 2mp+1}
  int np = wv >> 1;         // output s-row
  int quad = lane >> 4, l15 = lane & 15;
  int chq = quad * 8;

  f32x4 zf = {0.f, 0.f, 0.f, 0.f};
  f32x4 acc[2][4];  // [mi][nt]
#pragma unroll
  for (int mi = 0; mi < 2; ++mi)
#pragma unroll
    for (int nt = 0; nt < 4; ++nt) acc[mi][nt] = zf;
  const short8* ap = (const short8*)keff_bf;
  short8 abuf[2][2][2];  // [parity][mi][ks2]

#pragma unroll
  for (int p = 0; p < 2; ++p) {
    if (p) __syncthreads();   // pass-0 LDS reads complete before restage
    // stage ch-half p: 8 uint4 (64 ch) per (row, col)
    for (int rr = 0; rr < 4; ++rr) {
      int rs = s0 - 1 + rr;
      if (rs < 0 || rs >= S) {
        for (int i = t; i < 66 * 8; i += 256) {
          int col = i >> 3, q = i & 7;
          ((uint4*)&win[rr][col][0])[q] = z4;
        }
      } else {
        if (wt == 0 && t < 8) ((uint4*)&win[rr][0][0])[t] = z4;
        if (wt == 1 && t < 8) ((uint4*)&win[rr][65][0])[t] = z4;
        const uint4* src = (const uint4*)(ynhwc +
            (((size_t)bl * S + rs) * W + (w0 - 1 + c_lo)) * 128 + p * 64);
        int n4 = (c_hi - c_lo) * 8;   // 65*8 = 520
        for (int i = t; i < n4; i += 256) {
          int col = i >> 3, q = i & 7;
          ((uint4*)&win[rr][c_lo + col][0])[q] = src[col * 16 + q];
        }
      }
    }
    __syncthreads();

    // prefetch seg 0 A-fragments for this pass
#pragma unroll
    for (int ks2 = 0; ks2 < 2; ++ks2) {
      const int ks = p * 2 + ks2;
      abuf[0][0][ks2] = ap[((0 * 4 + ks) * 4 + 2 * mp) * 64 + lane];
      abuf[0][1][ks2] = ap[((0 * 4 + ks) * 4 + 2 * mp + 1) * 64 + lane];
    }

#pragma unroll
    for (int seg = 0; seg < 9; ++seg) {
      const int cur = seg & 1;
      const int nxt = cur ^ 1;
      if (seg < 8) {
#pragma unroll
        for (int ks2 = 0; ks2 < 2; ++ks2) {
          const int ks = p * 2 + ks2;
          abuf[nxt][0][ks2] = ap[(((seg + 1) * 4 + ks) * 4 + 2 * mp) * 64 + lane];
          abuf[nxt][1][ks2] = ap[(((seg + 1) * 4 + ks) * 4 + 2 * mp + 1) * 64 + lane];
        }
      }
      const int dr = seg / 3;
      const int dc = seg - dr * 3;
      const u16* rowbase = &win[np + dr][0][0];
#pragma unroll
      for (int ks2 = 0; ks2 < 2; ++ks2) {
#pragma unroll
        for (int nt = 0; nt < 4; ++nt) {
          short8 b = *(const short8*)(rowbase + (nt * 16 + l15 + dc) * 72 + chq + ks2 * 32);
          acc[0][nt] = __builtin_amdgcn_mfma_f32_16x16x32_bf16(abuf[cur][0][ks2], b, acc[0][nt], 0, 0, 0);
          acc[1][nt] = __builtin_amdgcn_mfma_f32_16x16x32_bf16(abuf[cur][1][ks2], b, acc[1][nt], 0, 0, 0);
        }
      }
    }
  }

  int s_out = s0 + np;
#pragma unroll
  for (int mi = 0; mi < 2; ++mi) {
#pragma unroll
    for (int reg = 0; reg < 4; ++reg) {
      int o = (2 * mp + mi) * 16 + quad * 4 + reg;
      float bias = biaseff[o];
      size_t rowoff = ((size_t)(bl * C + o) * S + s_out) * W;
#pragma unroll
      for (int nt = 0; nt < 4; ++nt)
        fused[rowoff + w0 + nt * 16 + l15] = f2bu(acc[mi][nt][reg] + bias);
    }
  }
}

// ---------------- layernorm (stats in-kernel) + residual ----------------
__global__ __launch_bounds__(256) void k_ln(
    const u16* __restrict__ fused,
    const float* __restrict__ ln_g, const float* __restrict__ ln_b,
    const float* __restrict__ x, float* __restrict__ out) {
  int blc = blockIdx.x;
  __shared__ u16 fs[SW];
  __shared__ float red[12];
  int t = threadIdx.x;
  const uint4* fp = (const uint4*)(fused + (size_t)blc * SW);
  float sm = 0.f, sq = 0.f;
  for (int i = t; i < SW / 8; i += 256) {
    uint4 v = fp[i];
    ((uint4*)fs)[i] = v;
    float f0 = bf_lo(v.x), f1 = bf_hi(v.x), f2 = bf_lo(v.y), f3 = bf_hi(v.y);
    float f4 = bf_lo(v.z), f5 = bf_hi(v.z), f6 = bf_lo(v.w), f7 = bf_hi(v.w);
    sm += f0 + f1 + f2 + f3 + f4 + f5 + f6 + f7;
    sq += f0 * f0 + f1 * f1 + f2 * f2 + f3 * f3 + f4 * f4 + f5 * f5 + f6 * f6 + f7 * f7;
  }
#pragma unroll
  for (int off = 32; off > 0; off >>= 1) {
    sm += __shfl_down(sm, off, 64);
    sq += __shfl_down(sq, off, 64);
  }
  int lane = t & 63, wid = t >> 6;
  if (lane == 0) { red[wid * 2] = sm; red[wid * 2 + 1] = sq; }
  __syncthreads();
  if (t == 0) {
    float S1 = red[0] + red[2] + red[4] + red[6];
    float S2 = red[1] + red[3] + red[5] + red[7];
    float mu = S1 * (1.f / SW);
    float var = S2 * (1.f / SW) - mu * mu;
    red[8] = mu;
    red[9] = rsqrtf(var + 1e-5f);
  }
  __syncthreads();
  float mu = red[8], rstd = red[9];
  const float* xp = x + (size_t)blc * SW;
  float* op = out + (size_t)blc * SW;
  for (int i = t; i < SW; i += 256)
    op[i] = (us2f(fs[i]) - mu) * rstd * ln_g[i] + ln_b[i] + xp[i];
}

extern "C" void kernel_launch(void* const* d_in, const int* in_sizes, int n_in,
                              void* d_out, int out_size, void* d_ws, size_t ws_size,
                              hipStream_t stream) {
  (void)in_sizes; (void)n_in; (void)out_size; (void)ws_size;
  const float* x       = (const float*)d_in[0];
  const float* nu_log  = (const float*)d_in[1];
  const float* th_log  = (const float*)d_in[2];
  const float* dnu     = (const float*)d_in[3];
  const float* dth     = (const float*)d_in[4];
  const float* w1      = (const float*)d_in[5];
  const float* b1      = (const float*)d_in[6];
  const float* w2      = (const float*)d_in[7];
  const float* b2      = (const float*)d_in[8];
  const float* fscale  = (const float*)d_in[9];
  const float* Ur      = (const float*)d_in[10];
  const float* Ui      = (const float*)d_in[11];
  const float* Vr      = (const float*)d_in[12];
  const float* Vi      = (const float*)d_in[13];
  const float* pWr     = (const float*)d_in[14];
  const float* pWi     = (const float*)d_in[15];
  const float* pbr     = (const float*)d_in[16];
  const float* pbi     = (const float*)d_in[17];
  const float* convr_k = (const float*)d_in[18];
  const float* convr_b = (const float*)d_in[19];
  const float* convi_k = (const float*)d_in[20];
  const float* convi_b = (const float*)d_in[21];
  const float* fuse_k  = (const float*)d_in[22];
  const float* fuse_b  = (const float*)d_in[23];
  const float* ln_g    = (const float*)d_in[24];
  const float* ln_b    = (const float*)d_in[25];
  float* out = (float*)d_out;

  char* ws = (char*)d_ws;
  float* lamr    = (float*)ws;
  float* lami    = lamr + 2048;
  float* gam     = lami + 2048;
  float* biaseff = gam + 2048;        // 64
  float* ctx     = biaseff + 64;      // 2048
  float* forcing = ctx + 2048;        // 131072
  float* ubuf    = forcing + 131072;  // 131072
  float* hbuf    = ubuf + 131072;     // 131072
  u16* keff_bf   = (u16*)(hbuf + 131072);       // 73728 u16 (144 KB)
  u16* aproj     = keff_bf + 73728;             // 16384 u16 (32 KB)
  size_t off = ((size_t)((char*)(aproj + 16384) - ws) + 255) & ~(size_t)255;
  u32* y_cm32    = (u32*)(ws + off);            // 32 MB (half-batch)
  u16* fused     = (u16*)y_cm32;                // ALIAS: live only after y_cm32 dead
  u16* ynhwc     = (u16*)(ws + off + (size_t)32 * 1024 * 1024);  // 64 MB
  // total ws ~ 97.8 MB

  k_prep<<<8, 256, 0, stream>>>(nu_log, th_log, dnu, dth, lamr, lami, gam);
  k_keff<<<289, 256, 0, stream>>>(fuse_k, fuse_b, convr_k, convr_b, convi_k, convi_b,
                                  keff_bf, biaseff);
  k_apack<<<64, 256, 0, stream>>>(pWr, pWi, aproj);
  k_enc<<<BL * C, 256, 0, stream>>>(x, Vr, Vi, Ur, Ui, ctx, ubuf);
  k_mlp<<<BL * 16, 256, 0, stream>>>(ctx, w1, b1, w2, b2, fscale, forcing);
  k_scan<<<16, 256, 0, stream>>>(lamr, lami, gam, forcing, ubuf, hbuf);
  k_decode<<<1024, 256, 0, stream>>>(hbuf, Ur, Ui, Vr, Vi, y_cm32, 0);
  k_proj<<<256, 256, 0, stream>>>(y_cm32, aproj, pbr, pbi, ynhwc, 0);
  k_decode<<<1024, 256, 0, stream>>>(hbuf, Ur, Ui, Vr, Vi, y_cm32, 16);
  k_proj<<<256, 256, 0, stream>>>(y_cm32, aproj, pbr, pbi, ynhwc, 16);
  k_conv<<<2048, 256, 0, stream>>>(ynhwc, keff_bf, biaseff, fused);
  k_ln<<<BL * C, 256, 0, stream>>>(fused, ln_g, ln_b, x, out);
}